// Round 8
// baseline (286.784 us; speedup 1.0000x reference)
//
#include <hip/hip_runtime.h>
#include <hip/hip_bf16.h>

#define B_ 8
#define C_ 128
#define F_ 16
#define N_ 512
#define CAP_ (N_ * N_)

typedef __attribute__((ext_vector_type(8))) short bf16x8;
typedef __attribute__((ext_vector_type(4))) float f32x4;

#define MFMA(a, b, c) __builtin_amdgcn_mfma_f32_16x16x32_bf16((a), (b), (c), 0, 0, 0)
#define SWZ(x) ((x) ^ ((((x) >> 8) & 7) << 4))

__device__ __forceinline__ ushort f2bf(float x) {
    union { __hip_bfloat16 h; ushort u; } cv;
    cv.h = __float2bfloat16(x);
    return cv.u;
}

// ---------------- fused: degree/zero-list (y<8) + weight prep (y==8) ----------------
__global__ __launch_bounds__(256) void k_prep(
    const float* __restrict__ Y, const float* __restrict__ Wd, const float* __restrict__ Wn,
    float* __restrict__ deg, int* __restrict__ cnt, int* __restrict__ list,
    float* __restrict__ Wsum, float* __restrict__ Wdiff, float* __restrict__ WsumT,
    ushort* __restrict__ WdT_bf, float* __restrict__ WnT)
{
    int t = threadIdx.x;
    if (blockIdx.y == 8) {
        for (int i = blockIdx.x * 256 + t; i < C_ * C_; i += 24 * 256) {
            int d = i >> 7, c = i & 127;
            const float* row = Wd + (size_t)d * (3 * C_);
            float w1 = row[c], w2 = row[C_ + c], w3 = row[2 * C_ + c];
            float ws = w1 + w3, wdf = w2 - w3;
            Wsum[i] = ws;
            Wdiff[i] = wdf;
            WsumT[(size_t)c * C_ + d] = ws;
            WdT_bf[(size_t)c * C_ + d] = f2bf(wdf);
            WnT[i] = Wn[(size_t)(i & 127) * C_ + (i >> 7)];
        }
        return;
    }
    __shared__ float red0[256], red1[256];
    int bg = blockIdx.x, vc = blockIdx.y;
    int b = bg / 3, g = bg % 3;
    int p = t & 31, q = t >> 5;
    int v = vc * 64 + p * 2;
    const float* Yp = Y + ((size_t)b * F_ + g) * N_ * N_;
    float d0 = 0.f, d1 = 0.f;
    #pragma unroll 4
    for (int i = 0; i < 64; ++i) {
        int u = q * 64 + i;
        float2 a = *(const float2*)(Yp + (size_t)u * N_ + v);
        if (a.x == 0.f) {
            int idx = atomicAdd(&cnt[bg], 1);
            list[(size_t)bg * CAP_ + idx] = (u << 9) | v;
        } else d0 += 1.f;
        if (a.y == 0.f) {
            int idx = atomicAdd(&cnt[bg], 1);
            list[(size_t)bg * CAP_ + idx] = (u << 9) | (v + 1);
        } else d1 += 1.f;
    }
    red0[t] = d0;
    red1[t] = d1;
    __syncthreads();
    if (t < 32) {
        float s0 = 0.f, s1 = 0.f;
        #pragma unroll
        for (int qq = 0; qq < 8; ++qq) { s0 += red0[qq * 32 + t]; s1 += red1[qq * 32 + t]; }
        deg[(size_t)bg * N_ + vc * 64 + t * 2]     = s0;
        deg[(size_t)bg * N_ + vc * 64 + t * 2 + 1] = s1;
    }
}

// ---------------- fused Gram + Meff per bf (512 threads, 8 waves) ----------------
// Gram: G = X X^T (c-space, K=N) via MFMA; A1[d] = sum_c WsumT[c][d]*G[c][d] reduced
// straight from accumulator frags; A2 = colsum(X). Then Meff = (Wn.diag(A2))*Wdiff
// with B-frags streamed from global (L2-hot); c0 = WnT^T * (A1 + A2.*bd).
__global__ __launch_bounds__(512) void k_gram_meff(
    const float* __restrict__ infos, const float* __restrict__ WsumT,
    const float* __restrict__ Wn, const float* __restrict__ WnT,
    const ushort* __restrict__ WdT_bf, const float* __restrict__ bd,
    ushort* __restrict__ Meff_bf, float* __restrict__ c0all)
{
    __shared__ char arena[32768];          // Xs dbuf (20KB) then Zl (32KB)
    short*  Xs = (short*)arena;            // [2][128][40]
    ushort* Zl = (ushort*)arena;
    __shared__ float A1red[8][132];
    __shared__ float A2red[512];
    __shared__ float A2l[C_], El[C_];
    int bf = blockIdx.x, t = threadIdx.x;
    int b = bf >> 4, f = bf & 15;
    const float* Xg = infos + ((size_t)b * C_ * F_ + f) * N_;

    int sc = t >> 2, suq = t & 3;          // staging: row sc, u-quads suq & suq+4
    float a2p = 0.f;
    float4 pre0, pre1;
    auto LOADREG = [&](int ks) {
        const float* p = Xg + (size_t)sc * (F_ * N_) + ks * 32 + suq * 4;
        pre0 = *(const float4*)p;
        pre1 = *(const float4*)(p + 16);
    };
    auto WRITELDS = [&](int buf) {
        a2p += pre0.x + pre0.y + pre0.z + pre0.w + pre1.x + pre1.y + pre1.z + pre1.w;
        short4 h0, h1;
        h0.x = (short)f2bf(pre0.x); h0.y = (short)f2bf(pre0.y);
        h0.z = (short)f2bf(pre0.z); h0.w = (short)f2bf(pre0.w);
        h1.x = (short)f2bf(pre1.x); h1.y = (short)f2bf(pre1.y);
        h1.z = (short)f2bf(pre1.z); h1.w = (short)f2bf(pre1.w);
        *(short4*)&Xs[buf * 5120 + sc * 40 + suq * 4]        = h0;
        *(short4*)&Xs[buf * 5120 + sc * 40 + (suq + 4) * 4]  = h1;
    };

    int l = t & 63, w = t >> 6;            // 8 waves
    int r = l & 15, q = l >> 4;
    f32x4 acc[8];
    #pragma unroll
    for (int ni = 0; ni < 8; ++ni) acc[ni] = (f32x4){0.f, 0.f, 0.f, 0.f};

    LOADREG(0);
    WRITELDS(0);
    for (int ks = 0; ks < 16; ++ks) {
        __syncthreads();
        if (ks < 15) LOADREG(ks + 1);
        const short* Xb = &Xs[(ks & 1) * 5120];
        bf16x8 av = *(const bf16x8*)&Xb[(w * 16 + r) * 40 + q * 8];
        #pragma unroll
        for (int ni = 0; ni < 8; ++ni) {
            bf16x8 bv = *(const bf16x8*)&Xb[(ni * 16 + r) * 40 + q * 8];
            acc[ni] = MFMA(av, bv, acc[ni]);
        }
        if (ks < 15) WRITELDS((ks + 1) & 1);
    }
    __syncthreads();
    A2red[t] = a2p;
    // A1 partials from accumulator frags: G rows w*16+q*4+j, col dl=ni*16+r
    #pragma unroll
    for (int ni = 0; ni < 8; ++ni) {
        int dl = ni * 16 + r;
        float p1 = 0.f;
        #pragma unroll
        for (int j = 0; j < 4; ++j)
            p1 += WsumT[(size_t)(w * 16 + q * 4 + j) * C_ + dl] * acc[ni][j];
        p1 += __shfl_xor(p1, 16);
        p1 += __shfl_xor(p1, 32);
        if (q == 0) A1red[w][dl] = p1;
    }
    __syncthreads();
    if (t < C_) {
        float a1 = 0.f;
        #pragma unroll
        for (int w8 = 0; w8 < 8; ++w8) a1 += A1red[w8][t];
        float a2 = A2red[t * 4] + A2red[t * 4 + 1] + A2red[t * 4 + 2] + A2red[t * 4 + 3];
        A2l[t] = a2;
        El[t] = a1 + a2 * bd[t];
    }
    __syncthreads();
    // ---- Z = Wn . diag(A2) staged swizzled into Zl (arena reuse) ----
    #pragma unroll
    for (int it = 0; it < 4; ++it) {
        int idx = it * 512 + t;                  // 0..2047
        int o = idx >> 4, ch = idx & 15;
        const float4 w0 = *(const float4*)&Wn[(size_t)o * C_ + ch * 8];
        const float4 w1 = *(const float4*)&Wn[(size_t)o * C_ + ch * 8 + 4];
        bf16x8 z;
        z[0] = (short)f2bf(w0.x * A2l[ch * 8 + 0]);
        z[1] = (short)f2bf(w0.y * A2l[ch * 8 + 1]);
        z[2] = (short)f2bf(w0.z * A2l[ch * 8 + 2]);
        z[3] = (short)f2bf(w0.w * A2l[ch * 8 + 3]);
        z[4] = (short)f2bf(w1.x * A2l[ch * 8 + 4]);
        z[5] = (short)f2bf(w1.y * A2l[ch * 8 + 5]);
        z[6] = (short)f2bf(w1.z * A2l[ch * 8 + 6]);
        z[7] = (short)f2bf(w1.w * A2l[ch * 8 + 7]);
        *(bf16x8*)((char*)Zl + SWZ(o * 256 + ch * 16)) = z;
    }
    __syncthreads();
    f32x4 acc2[8];
    #pragma unroll
    for (int ni = 0; ni < 8; ++ni) acc2[ni] = (f32x4){0.f, 0.f, 0.f, 0.f};
    #pragma unroll
    for (int ks = 0; ks < 4; ++ks) {
        bf16x8 av = *(const bf16x8*)((char*)Zl + SWZ((w * 16 + r) * 256 + ks * 64 + q * 16));
        #pragma unroll
        for (int ni = 0; ni < 8; ++ni) {
            bf16x8 bv = *(const bf16x8*)&WdT_bf[(size_t)(ni * 16 + r) * C_ + ks * 32 + q * 8];
            acc2[ni] = MFMA(av, bv, acc2[ni]);
        }
    }
    __syncthreads();     // Zl reads done; reuse as linear repack
    #pragma unroll
    for (int ni = 0; ni < 8; ++ni) {
        int o = w * 16 + q * 4;
        int c = ni * 16 + r;
        #pragma unroll
        for (int j = 0; j < 4; ++j) Zl[(o + j) * C_ + c] = f2bf(acc2[ni][j]);
    }
    __syncthreads();
    #pragma unroll
    for (int it = 0; it < 4; ++it) {
        int idx = it * 512 + t;
        int rowi = idx >> 4, ch = idx & 15;
        *(bf16x8*)&Meff_bf[(size_t)bf * 16384 + rowi * C_ + ch * 8] =
            *(const bf16x8*)&Zl[rowi * C_ + ch * 8];
    }
    if (t < C_) {
        float s = 0.f;
        for (int c = 0; c < C_; ++c) s += WnT[(size_t)c * C_ + t] * El[c];
        c0all[(size_t)bf * C_ + t] = s;
    }
}

// ---------------- final: out = relu((Meff*X + c0)/deg + bn); A-frags direct from global ----------------
__global__ __launch_bounds__(256) void k_final(
    const float* __restrict__ infos, const ushort* __restrict__ Meff_bf,
    const float* __restrict__ c0all, const float* __restrict__ deg,
    const int* __restrict__ cnt, const int* __restrict__ list,
    const float* __restrict__ Wsum, const float* __restrict__ Wdiff,
    const float* __restrict__ Wn, const float* __restrict__ bd, const float* __restrict__ bn,
    float* __restrict__ out)
{
    __shared__ char arena[33792];          // Xv (16KB) ; reused as Sl 128x66 f32 (33KB)
    ushort* Xv = (ushort*)arena;
    float*  Sl = (float*)arena;
    __shared__ float Xu[C_], Xvf[C_], NC[C_], corrv[C_];
    int bf = blockIdx.x, vb = blockIdx.y, t = threadIdx.x;
    int b = bf >> 4, f = bf & 15;
    int g = (f == 0) ? 0 : ((f <= 11) ? 1 : 2);
    int bg = b * 3 + g;
    int v0 = vb * 64;
    const float* Xg = infos + ((size_t)b * C_ * F_ + f) * N_;
    const ushort* Meffp = Meff_bf + (size_t)bf * 16384;

    #pragma unroll
    for (int it = 0; it < 4; ++it) {
        int idx = it * 256 + t;
        int cp = idx >> 4, vq = idx & 15;
        const float* r0 = Xg + (size_t)(2 * cp) * (F_ * N_) + v0 + vq * 4;
        const float* r1 = r0 + (F_ * N_);
        float4 x0 = *(const float4*)r0;
        float4 x1 = *(const float4*)r1;
        float e0[4] = {x0.x, x0.y, x0.z, x0.w};
        float e1[4] = {x1.x, x1.y, x1.z, x1.w};
        #pragma unroll
        for (int j = 0; j < 4; ++j) {
            int vloc = vq * 4 + j;
            unsigned word = (unsigned)f2bf(e0[j]) | ((unsigned)f2bf(e1[j]) << 16);
            *(unsigned*)((char*)Xv + SWZ(vloc * 256 + cp * 4)) = word;
        }
    }
    __syncthreads();

    int l = t & 63, w = t >> 6, r = l & 15, q = l >> 4;
    f32x4 acc[2][4];
    #pragma unroll
    for (int mi = 0; mi < 2; ++mi)
        #pragma unroll
        for (int ni = 0; ni < 4; ++ni) acc[mi][ni] = (f32x4){0.f, 0.f, 0.f, 0.f};
    #pragma unroll
    for (int ks = 0; ks < 4; ++ks) {
        int ke = ks * 32 + q * 8;
        bf16x8 a0 = *(const bf16x8*)&Meffp[(size_t)(w * 32 + r) * C_ + ke];
        bf16x8 a1 = *(const bf16x8*)&Meffp[(size_t)(w * 32 + 16 + r) * C_ + ke];
        #pragma unroll
        for (int nt = 0; nt < 4; ++nt) {
            bf16x8 bb = *(const bf16x8*)((char*)Xv + SWZ((nt * 16 + r) * 256 + ks * 64 + q * 16));
            acc[0][nt] = MFMA(a0, bb, acc[0][nt]);
            acc[1][nt] = MFMA(a1, bb, acc[1][nt]);
        }
    }

    // ---- rare zero-edge corrections ----
    int nz = cnt[bg];
    for (int e = 0; e < nz; ++e) {
        int p = list[(size_t)bg * CAP_ + e];
        int u = p >> 9, v = p & 511;
        if ((v >> 6) != vb) continue;
        int vloc = v - v0;
        __syncthreads();
        if (t < C_) {
            Xu[t]  = Xg[(size_t)t * (F_ * N_) + u];
            Xvf[t] = Xg[(size_t)t * (F_ * N_) + v];
        }
        __syncthreads();
        if (t < C_) {
            float s = 0.f, dv = 0.f;
            const float* wsr = Wsum + (size_t)t * C_;
            const float* wdr = Wdiff + (size_t)t * C_;
            for (int c = 0; c < C_; ++c) { s += wsr[c] * Xu[c]; dv += wdr[c] * Xvf[c]; }
            NC[t] = Xu[t] * (s + dv + bd[t]);
        }
        __syncthreads();
        if (t < C_) {
            float s = 0.f;
            const float* wnr = Wn + (size_t)t * C_;
            for (int c = 0; c < C_; ++c) s += wnr[c] * NC[c];
            corrv[t] = s;
        }
        __syncthreads();
        int ntv = vloc >> 4;
        #pragma unroll
        for (int nt = 0; nt < 4; ++nt) {
            if (nt == ntv && r == (vloc & 15)) {
                #pragma unroll
                for (int mi = 0; mi < 2; ++mi)
                    #pragma unroll
                    for (int j = 0; j < 4; ++j)
                        acc[mi][nt][j] -= corrv[w * 32 + mi * 16 + q * 4 + j];
            }
        }
    }

    // ---- epilogue: /deg + bias + relu, bounce through LDS, float4 stores ----
    float c0v[2][4], bnv[2][4];
    #pragma unroll
    for (int mi = 0; mi < 2; ++mi)
        #pragma unroll
        for (int j = 0; j < 4; ++j) {
            int o = w * 32 + mi * 16 + q * 4 + j;
            c0v[mi][j] = c0all[(size_t)bf * C_ + o];
            bnv[mi][j] = bn[o];
        }
    __syncthreads();   // Xv reads complete; arena becomes Sl
    #pragma unroll
    for (int nt = 0; nt < 4; ++nt) {
        int v = v0 + nt * 16 + r;
        float dg = fmaxf(deg[(size_t)bg * N_ + v], 1.f);
        #pragma unroll
        for (int mi = 0; mi < 2; ++mi) {
            int o = w * 32 + mi * 16 + q * 4;
            #pragma unroll
            for (int j = 0; j < 4; ++j) {
                float val = fmaxf((acc[mi][nt][j] + c0v[mi][j]) / dg + bnv[mi][j], 0.f);
                Sl[(o + j) * 66 + nt * 16 + r] = val;
            }
        }
    }
    __syncthreads();
    {
        int o = t >> 1, half = t & 1;
        float* src = &Sl[o * 66 + half * 32];
        float* dst = &out[((size_t)b * C_ + o) * (F_ * N_) + (size_t)f * N_ + v0 + half * 32];
        #pragma unroll
        for (int j = 0; j < 8; ++j)
            *(float4*)(dst + j * 4) = *(const float4*)(src + j * 4);
    }
}

extern "C" void kernel_launch(void* const* d_in, const int* in_sizes, int n_in,
                              void* d_out, int out_size, void* d_ws, size_t ws_size,
                              hipStream_t stream)
{
    const float* Y     = (const float*)d_in[0];
    const float* infos = (const float*)d_in[1];
    const float* Wd    = (const float*)d_in[2];
    const float* bd    = (const float*)d_in[3];
    const float* Wn    = (const float*)d_in[4];
    const float* bn    = (const float*)d_in[5];
    float* out = (float*)d_out;
    float* ws  = (float*)d_ws;

    float*  deg     = ws;                              // 12288
    int*    cnt     = (int*)(ws + 12288);              // 32 ints
    float*  Wsum    = ws + 12320;                      // 16384
    float*  Wdiff   = Wsum + 16384;
    float*  WsumT   = Wdiff + 16384;
    float*  WnT     = WsumT + 16384;
    float*  c0all   = WnT + 16384;
    ushort* WdT_bf  = (ushort*)(c0all + 16384);        // 16384 ushort = 8192 f
    ushort* Meff_bf = (ushort*)(c0all + 16384 + 8192); // 2097152 ushort
    int*    list    = (int*)(c0all + 16384 + 8192 + 1048576);

    hipMemsetAsync(cnt, 0, 32 * sizeof(int), stream);
    k_prep<<<dim3(24, 9), 256, 0, stream>>>(Y, Wd, Wn, deg, cnt, list,
                                            Wsum, Wdiff, WsumT, WdT_bf, WnT);
    k_gram_meff<<<B_ * F_, 512, 0, stream>>>(infos, WsumT, Wn, WnT, WdT_bf, bd,
                                             Meff_bf, c0all);
    k_final<<<dim3(B_ * F_, 8), 256, 0, stream>>>(infos, Meff_bf, c0all, deg, cnt, list,
                                                  Wsum, Wdiff, Wn, bd, bn, out);
}